// Round 5
// baseline (124.790 us; speedup 1.0000x reference)
//
#include <hip/hip_runtime.h>
#include <stdint.h>

#define BS 8192
#define DD 128
#define L2E 1.4426950408889634f
#define LN2 0.6931471805599453f

typedef __attribute__((ext_vector_type(8))) short short8;
typedef __attribute__((ext_vector_type(4))) float float4v;

#if __has_builtin(__builtin_amdgcn_exp2f)
#define EXP2(x) __builtin_amdgcn_exp2f(x)
#else
#define EXP2(x) exp2f(x)
#endif

__device__ __forceinline__ float bf2f(short s) {
  union { unsigned u; float f; } c;
  c.u = ((unsigned)(unsigned short)s) << 16;
  return c.f;
}
__device__ __forceinline__ short f2bf(float f) {
  union { float f; unsigned u; } c; c.f = f;
  unsigned u = c.u + 0x7FFFu + ((c.u >> 16) & 1u);
  return (short)(u >> 16);
}

// Fragment-ordered bf16 layout ("xnbF"): 16-byte chunk index for (row, kc):
//   chunk(row,kc) = (row>>4)*256 + (kc>>2)*64 + (kc&3)*16 + (row&15)
// A wave load F[g*256 + t*64 + lane] gives lane (quad=lane>>4, col=lane&15) the
// 8 bf16 of row g*16+col, k-chunk 4t+quad — exactly the mfma_f32_16x16x32_bf16
// A/B fragment layout (verified: rounds 2-4 passed absmax=0).

// K1: normalize rows -> xnbF, per-class column sums (register-accumulated, then
// LDS, then 4-way-split global atomics: chain 64), counts, mask mf, zero-init.
__global__ __launch_bounds__(256) void k_norm(const float* __restrict__ data,
                                              const int* __restrict__ label,
                                              char* __restrict__ xnbF,
                                              float* __restrict__ gh4,
                                              int* __restrict__ cnt4,
                                              float* __restrict__ Zr,
                                              float* __restrict__ Ur,
                                              float* __restrict__ Vr,
                                              float* __restrict__ mf) {
  __shared__ float shg[256];
  __shared__ int shc[2];
  int tid = threadIdx.x, wave = tid >> 6, lane = tid & 63;
  int lh = lane & 31, rsel = lane >> 5;
  if (tid < 2) shc[tid] = 0;
  shg[tid] = 0.f;
  int rowbase = blockIdx.x * 32;
  if (tid < 32) {  // zero this block's accumulator rows (workspace is poisoned)
    int row = rowbase + tid;
    Zr[row] = 0.f; Ur[row] = 0.f; Vr[row] = 0.f;
    mf[row] = (label[row] == 0) ? 1.f : 0.f;
  }
  __syncthreads();

  float a00 = 0.f, a01 = 0.f, a02 = 0.f, a03 = 0.f;  // class-0 column partials
  float a10 = 0.f, a11 = 0.f, a12 = 0.f, a13 = 0.f;  // class-1
  int c0 = 0, c1 = 0;
#pragma unroll
  for (int it = 0; it < 4; ++it) {
    int row = rowbase + it * 8 + wave * 2 + rsel;
    float4 v = *(const float4*)&data[row * DD + lh * 4];  // 16B/lane coalesced
    float ss = v.x * v.x + v.y * v.y + v.z * v.z + v.w * v.w;
#pragma unroll
    for (int off = 16; off; off >>= 1) ss += __shfl_xor(ss, off);  // 32-lane
    float rn = 1.f / fmaxf(sqrtf(ss), 1e-12f);  // F.normalize eps clamp
    float x0 = v.x * rn, x1 = v.y * rn, x2 = v.z * rn, x3 = v.w * rn;

    unsigned pk0 = (unsigned)(unsigned short)f2bf(x0) |
                   ((unsigned)(unsigned short)f2bf(x1) << 16);
    unsigned pk1 = (unsigned)(unsigned short)f2bf(x2) |
                   ((unsigned)(unsigned short)f2bf(x3) << 16);
    int kc = lh >> 1;
    size_t chunk = (size_t)(row >> 4) * 256 + (size_t)(kc >> 2) * 64 +
                   (size_t)(kc & 3) * 16 + (row & 15);
    *(uint2*)(xnbF + chunk * 16 + (lh & 1) * 8) = make_uint2(pk0, pk1);

    int lab = label[row];  // half-wave uniform
    if (lab == 0) {
      a00 += x0; a01 += x1; a02 += x2; a03 += x3;
      if (lh == 0) c0++;
    } else {
      a10 += x0; a11 += x1; a12 += x2; a13 += x3;
      if (lh == 0) c1++;
    }
  }
  int base = lh * 4;  // 8 colliders per address (4 waves x 2 halves)
  atomicAdd(&shg[base + 0], a00); atomicAdd(&shg[base + 1], a01);
  atomicAdd(&shg[base + 2], a02); atomicAdd(&shg[base + 3], a03);
  atomicAdd(&shg[128 + base + 0], a10); atomicAdd(&shg[128 + base + 1], a11);
  atomicAdd(&shg[128 + base + 2], a12); atomicAdd(&shg[128 + base + 3], a13);
  if (lh == 0) { atomicAdd(&shc[0], c0); atomicAdd(&shc[1], c1); }
  __syncthreads();
  // 4-way-split targets: per-address global atomic chain is 64, not 256
  atomicAdd(&gh4[(blockIdx.x & 3) * 256 + tid], shg[tid]);
  if (tid < 2) atomicAdd(&cnt4[(blockIdx.x & 3) * 2 + tid], shc[tid]);
}

// K3: barrier-free flash-style Gram-row reductions, DEEP-PIPELINED.
// Round-4 post-mortem: VGPR=80 == ZUV(48)+B(32) exactly -> A-frags + c-temps
// live in AGPRs (fine on gfx950; VGPR_Count doesn't show them). No remat, no
// spill. Remaining stall candidates: 1-deep prefetch exposes L2 latency, and
// the within-wave serial chain MFMA->acc_read->EXP2->next-group. Fixes here:
//   (a) 2-group-ahead B prefetch via P/Q register ping-pong (gg+=2 loop);
//   (b) two c-tile sets so the exp epilogue of group g-1 runs between
//       MFMA-issue(g) and acc-read(g) (T15-style MFMA/VALU overlap).
__global__ __launch_bounds__(256, 2) void k_main(const short* __restrict__ xnbF,
                                                 const int* __restrict__ label,
                                                 const float* __restrict__ mf,
                                                 const float* __restrict__ scale,
                                                 float* __restrict__ Zr,
                                                 float* __restrict__ Ur,
                                                 float* __restrict__ Vr) {
  int tid = threadIdx.x, wave = tid >> 6, lane = tid & 63;
  int quad = lane >> 4, col = lane & 15;
  int rbI = blockIdx.x >> 5;   // 0..31: 256-row block
  int sl = blockIdx.x & 31;    // 0..31: 256-col slice
  float se2 = __expf(scale[0]) * L2E;  // exp(scale)*log2(e): log2-domain logits

  const short8* F = (const short8*)xnbF;  // indexed by 16B chunk

  // A fragments: 4 row-sets of 16 rows (64 rows/wave); scaled by se2 once.
  int gA = rbI * 16 + wave * 4;
  short8 af[4][4];
#pragma unroll
  for (int s = 0; s < 4; ++s)
#pragma unroll
    for (int t = 0; t < 4; ++t) {
      short8 a = F[(size_t)(gA + s) * 256 + t * 64 + lane];
#pragma unroll
      for (int i = 0; i < 8; ++i) a[i] = f2bf(bf2f(a[i]) * se2);
      af[s][t] = a;
    }

  float4v Zc0 = {0.f,0.f,0.f,0.f}, Zc1 = Zc0, Zc2 = Zc0, Zc3 = Zc0;
  float4v Uc0 = Zc0, Uc1 = Zc0, Uc2 = Zc0, Uc3 = Zc0;
  float4v Vc0 = Zc0, Vc1 = Zc0, Vc2 = Zc0, Vc3 = Zc0;

  const short8* FB = F + (size_t)(sl * 16) * 256 + lane;
  const float* MB = mf + sl * 256 + col;

  short8 pA0, pA1, pA2, pA3, pB0, pB1, pB2, pB3;
  float mA, mB_;
  float4v cP0, cP1, cP2, cP3, cQ0, cQ1, cQ2, cQ3;

#define LOADP(g) { const short8* p_ = FB + (size_t)(g) * 256;                  \
    pA0 = p_[0]; pA1 = p_[64]; pA2 = p_[128]; pA3 = p_[192];                   \
    mA = MB[(g) * 16]; }
#define LOADQ(g) { const short8* p_ = FB + (size_t)(g) * 256;                  \
    pB0 = p_[0]; pB1 = p_[64]; pB2 = p_[128]; pB3 = p_[192];                   \
    mB_ = MB[(g) * 16]; }
#define MFMA1(cc, s, b0, b1, b2, b3)                                           \
    cc = (float4v){0.f, 0.f, 0.f, 0.f};                                        \
    cc = __builtin_amdgcn_mfma_f32_16x16x32_bf16(af[s][0], b0, cc, 0, 0, 0);   \
    cc = __builtin_amdgcn_mfma_f32_16x16x32_bf16(af[s][1], b1, cc, 0, 0, 0);   \
    cc = __builtin_amdgcn_mfma_f32_16x16x32_bf16(af[s][2], b2, cc, 0, 0, 0);   \
    cc = __builtin_amdgcn_mfma_f32_16x16x32_bf16(af[s][3], b3, cc, 0, 0, 0);
#define MFMA4(c0, c1, c2, c3, b0, b1, b2, b3)                                  \
    { MFMA1(c0, 0, b0, b1, b2, b3) MFMA1(c1, 1, b0, b1, b2, b3)                \
      MFMA1(c2, 2, b0, b1, b2, b3) MFMA1(c3, 3, b0, b1, b2, b3) }
#define EPIROW(cc, Zc, Uc, Vc, mm)                                             \
    { _Pragma("unroll")                                                        \
      for (int r = 0; r < 4; ++r) { /* C/D: col=lane&15, row=quad*4+r (m89) */ \
        float l = (cc)[r], e = EXP2(l);  /* log2-domain, |l|<=20.6: safe */    \
        (Zc)[r] += e;                                                          \
        (Uc)[r] = fmaf(e, l, (Uc)[r]);                                         \
        (Vc)[r] = fmaf((mm), e, (Vc)[r]);                                      \
      } }
#define EPI4(c0, c1, c2, c3, mm)                                               \
    EPIROW(c0, Zc0, Uc0, Vc0, mm) EPIROW(c1, Zc1, Uc1, Vc1, mm)                \
    EPIROW(c2, Zc2, Uc2, Vc2, mm) EPIROW(c3, Zc3, Uc3, Vc3, mm)

  // Prologue: fill the 2-deep pipe.  P = even groups, Q = odd groups.
  LOADP(0); LOADQ(1);
  MFMA4(cP0, cP1, cP2, cP3, pA0, pA1, pA2, pA3);  // group 0
  float mPe = mA;
  LOADP(2);
  // Steady state: each half-body consumes a group loaded 2 groups earlier and
  // runs the PREVIOUS group's exp epilogue between MFMA-issue and acc-read.
#pragma unroll 1
  for (int g = 1; g < 14; g += 2) {
    MFMA4(cQ0, cQ1, cQ2, cQ3, pB0, pB1, pB2, pB3);  // group g
    float mQe = mB_;
    LOADQ(g + 2);
    EPI4(cP0, cP1, cP2, cP3, mPe);                  // epilogue group g-1
    MFMA4(cP0, cP1, cP2, cP3, pA0, pA1, pA2, pA3);  // group g+1
    mPe = mA;
    if (g + 3 < 16) LOADP(g + 3);
    EPI4(cQ0, cQ1, cQ2, cQ3, mQe);                  // epilogue group g
  }
  // Tail: groups 14 (in cP) and 15 (in pB, loaded at g=13).
  MFMA4(cQ0, cQ1, cQ2, cQ3, pB0, pB1, pB2, pB3);    // group 15
  float mQe = mB_;
  EPI4(cP0, cP1, cP2, cP3, mPe);                    // epilogue group 14
  EPI4(cQ0, cQ1, cQ2, cQ3, mQe);                    // epilogue group 15
#undef LOADP
#undef LOADQ
#undef MFMA1
#undef MFMA4
#undef EPIROW
#undef EPI4

  // reduce across the 16 column-lanes sharing each output row, then atomics
#define EMIT(s, Zc, Uc, Vc)                                                    \
  {                                                                            \
    _Pragma("unroll")                                                          \
    for (int r = 0; r < 4; ++r) {                                              \
      float z = Zc[r], u = Uc[r], v0 = Vc[r];                                  \
      _Pragma("unroll")                                                        \
      for (int off = 1; off < 16; off <<= 1) {                                 \
        z += __shfl_xor(z, off);                                               \
        u += __shfl_xor(u, off);                                               \
        v0 += __shfl_xor(v0, off);                                             \
      }                                                                        \
      if (col == 0) {                                                          \
        int row = rbI * 256 + wave * 64 + s * 16 + quad * 4 + r;               \
        int lab = label[row];                                                  \
        float v = (lab == 0) ? v0 : (z - v0);                                  \
        atomicAdd(&Zr[row], z);                                                \
        atomicAdd(&Ur[row], u * LN2); /* log2-domain -> nats */                \
        atomicAdd(&Vr[row], v);                                                \
      }                                                                        \
    }                                                                          \
  }
  EMIT(0, Zc0, Uc0, Vc0)
  EMIT(1, Zc1, Uc1, Vc1)
  EMIT(2, Zc2, Uc2, Vc2)
  EMIT(3, Zc3, Uc3, Vc3)
#undef EMIT
}

// K4: per-row loss; S,T via closed-form dots with class sums. 256 blocks x 32
// rows; per-block partial + agent-scope last-block ticket does the final sum
// in-kernel (saves the k_sum launch).
__global__ __launch_bounds__(256) void k_final(const float* __restrict__ data,
                                               const int* __restrict__ label,
                                               const float* __restrict__ scale,
                                               const float* __restrict__ gh4,
                                               const int* __restrict__ cnt4,
                                               const float* __restrict__ Zr,
                                               const float* __restrict__ Ur,
                                               const float* __restrict__ Vr,
                                               float* __restrict__ partial,
                                               int* __restrict__ ticket,
                                               float* __restrict__ out) {
  __shared__ float hsum[256];
  __shared__ float bsum[4];
  __shared__ int lastb;
  int tid = threadIdx.x, wave = tid >> 6, lane = tid & 63;
  int lh = lane & 31, rsel = lane >> 5;
  hsum[tid] = gh4[tid] + gh4[256 + tid] + gh4[512 + tid] + gh4[768 + tid];
  __syncthreads();

  float se = __expf(scale[0]);
  float c0 = (float)(cnt4[0] + cnt4[2] + cnt4[4] + cnt4[6]);
  float c1 = (float)(cnt4[1] + cnt4[3] + cnt4[5] + cnt4[7]);
  float4 h0 = *(const float4*)&hsum[lh * 4];
  float4 h1 = *(const float4*)&hsum[128 + lh * 4];

  float local = 0.f;
#pragma unroll
  for (int it = 0; it < 4; ++it) {
    int row = blockIdx.x * 32 + it * 8 + wave * 2 + rsel;
    float4 v = *(const float4*)&data[row * DD + lh * 4];
    float ss = v.x * v.x + v.y * v.y + v.z * v.z + v.w * v.w;
#pragma unroll
    for (int off = 16; off; off >>= 1) ss += __shfl_xor(ss, off);
    float rn = 1.f / fmaxf(sqrtf(ss), 1e-12f);

    int lab = label[row];
    float sg = v.x * (h0.x + h1.x) + v.y * (h0.y + h1.y) +
               v.z * (h0.z + h1.z) + v.w * (h0.w + h1.w);
    float sh_ = (lab == 0)
                    ? (v.x * h0.x + v.y * h0.y + v.z * h0.z + v.w * h0.w)
                    : (v.x * h1.x + v.y * h1.y + v.z * h1.z + v.w * h1.w);
#pragma unroll
    for (int off = 16; off; off >>= 1) {
      sg += __shfl_xor(sg, off);
      sh_ += __shfl_xor(sh_, off);
    }
    if (lh == 0) {
      float cc = (lab == 0) ? c0 : c1;
      float a = __expf(1.f / cc);
      float Zq = cc * a + ((float)BS - cc);
      float S = se * sg * rn, T = se * sh_ * rn;
      float Zv = Zr[row], Uv = Ur[row], Vv = Vr[row];
      // loss_i = a/Zq - (S+(a-1)T)/Zq + U/Z - V/(c*Z)  (M_i, log Zq cancelled)
      local += a / Zq - (S + (a - 1.f) * T) / Zq + Uv / Zv - Vv / (cc * Zv);
    }
  }
  // local is nonzero only on lanes 0 and 32; full-wave reduce is safe
#pragma unroll
  for (int off = 32; off; off >>= 1) local += __shfl_xor(local, off);
  if (lane == 0) bsum[wave] = local;
  __syncthreads();
  if (tid == 0) {
    float psum = bsum[0] + bsum[1] + bsum[2] + bsum[3];
    // agent-scope release store -> visible across XCD L2s at coherence point
    __hip_atomic_store(&partial[blockIdx.x], psum, __ATOMIC_RELEASE,
                       __HIP_MEMORY_SCOPE_AGENT);
    int t = __hip_atomic_fetch_add(ticket, 1, __ATOMIC_ACQ_REL,
                                   __HIP_MEMORY_SCOPE_AGENT);
    lastb = (t == 255);
  }
  __syncthreads();
  if (lastb) {  // last block sums all 256 partials and stores the result
    float v = __hip_atomic_load(&partial[tid], __ATOMIC_ACQUIRE,
                                __HIP_MEMORY_SCOPE_AGENT);
#pragma unroll
    for (int off = 32; off; off >>= 1) v += __shfl_xor(v, off);
    if (lane == 0) bsum[wave] = v;
    __syncthreads();
    if (tid == 0)
      out[0] = (bsum[0] + bsum[1] + bsum[2] + bsum[3]) * (0.5f / (float)BS);
  }
}

extern "C" void kernel_launch(void* const* d_in, const int* in_sizes, int n_in,
                              void* d_out, int out_size, void* d_ws, size_t ws_size,
                              hipStream_t stream) {
  const float* data = (const float*)d_in[0];
  const float* scale = (const float*)d_in[1];
  const int* label = (const int*)d_in[2];
  char* ws = (char*)d_ws;
  // ws layout (bytes):
  //   0        xnbF bf16 fragment-order [8192*128]   2 MB
  //   2097152  Zr     f32 [8192]
  //   2129920  Ur     f32 [8192]
  //   2162688  Vr     f32 [8192]
  //   2195456  gh4    f32 [4][256]  (4-way split class sums)
  //   2199552  cnt4   int [8]       (4-way split class counts)
  //   2199584  ticket int [1]
  //   2199588  partial f32 [256]
  //   2200640  mf     f32 [8192]
  char* xnbF = ws;
  float* Zr = (float*)(ws + 2097152);
  float* Ur = (float*)(ws + 2129920);
  float* Vr = (float*)(ws + 2162688);
  float* gh4 = (float*)(ws + 2195456);
  int* cnt4 = (int*)(ws + 2199552);
  int* ticket = (int*)(ws + 2199584);
  float* partial = (float*)(ws + 2199588);
  float* mf = (float*)(ws + 2200640);

  // gh4+cnt4+ticket (4132 B); Zr/Ur/Vr/mf zeroed in k_norm; partial fully
  // written by k_final before any read; out stored by k_final's last block.
  hipMemsetAsync(ws + 2195456, 0, 4132, stream);

  k_norm<<<256, 256, 0, stream>>>(data, label, xnbF, gh4, cnt4, Zr, Ur, Vr, mf);
  k_main<<<1024, 256, 0, stream>>>((const short*)xnbF, label, mf, scale, Zr, Ur, Vr);
  k_final<<<256, 256, 0, stream>>>(data, label, scale, gh4, cnt4, Zr, Ur, Vr,
                                   partial, ticket, (float*)d_out);
}

// Round 6
// 108.704 us; speedup vs baseline: 1.1480x; 1.1480x over previous
//
#include <hip/hip_runtime.h>
#include <stdint.h>

#define BS 8192
#define DD 128
#define L2E 1.4426950408889634f
#define LN2 0.6931471805599453f

typedef __attribute__((ext_vector_type(8))) short short8;
typedef __attribute__((ext_vector_type(4))) float float4v;

#if __has_builtin(__builtin_amdgcn_exp2f)
#define EXP2(x) __builtin_amdgcn_exp2f(x)
#else
#define EXP2(x) exp2f(x)
#endif

__device__ __forceinline__ float bf2f(short s) {
  union { unsigned u; float f; } c;
  c.u = ((unsigned)(unsigned short)s) << 16;
  return c.f;
}
__device__ __forceinline__ short f2bf(float f) {
  union { float f; unsigned u; } c; c.f = f;
  unsigned u = c.u + 0x7FFFu + ((c.u >> 16) & 1u);
  return (short)(u >> 16);
}

// Fragment-ordered bf16 layout ("xnbF"): 16-byte chunk index for (row, kc):
//   chunk(row,kc) = (row>>4)*256 + (kc>>2)*64 + (kc&3)*16 + (row&15)
// A wave load F[g*256 + t*64 + lane] gives lane (quad=lane>>4, col=lane&15) the
// 8 bf16 of row g*16+col, k-chunk 4t+quad — the verified mfma_f32_16x16x32_bf16
// A/B fragment layout (rounds 2-5 passed absmax=0 with it). Bonus: a 64-col
// panel is 1024 CONTIGUOUS chunks, so LDS staging is a linear 16KB memcpy that
// global_load_lds can do (wave-uniform base + lane*16) and ds_reads of it are
// lane-contiguous (conflict-free, no swizzle needed).

// K1: normalize rows -> xnbF, per-class column sums (register-accumulated, then
// LDS, then 8-way-split global atomics: chain 32), counts, mask mf, zero-init.
__global__ __launch_bounds__(256) void k_norm(const float* __restrict__ data,
                                              const int* __restrict__ label,
                                              char* __restrict__ xnbF,
                                              float* __restrict__ gh8,
                                              int* __restrict__ cnt8,
                                              float* __restrict__ Zr,
                                              float* __restrict__ Ur,
                                              float* __restrict__ Vr,
                                              float* __restrict__ mf) {
  __shared__ float shg[256];
  __shared__ int shc[2];
  int tid = threadIdx.x, wave = tid >> 6, lane = tid & 63;
  int lh = lane & 31, rsel = lane >> 5;
  if (tid < 2) shc[tid] = 0;
  shg[tid] = 0.f;
  int rowbase = blockIdx.x * 32;
  if (tid < 32) {  // zero this block's accumulator rows (workspace is poisoned)
    int row = rowbase + tid;
    Zr[row] = 0.f; Ur[row] = 0.f; Vr[row] = 0.f;
    mf[row] = (label[row] == 0) ? 1.f : 0.f;
  }
  __syncthreads();

  float a00 = 0.f, a01 = 0.f, a02 = 0.f, a03 = 0.f;  // class-0 column partials
  float a10 = 0.f, a11 = 0.f, a12 = 0.f, a13 = 0.f;  // class-1
  int c0 = 0, c1 = 0;
#pragma unroll
  for (int it = 0; it < 4; ++it) {
    int row = rowbase + it * 8 + wave * 2 + rsel;
    float4 v = *(const float4*)&data[row * DD + lh * 4];  // 16B/lane coalesced
    float ss = v.x * v.x + v.y * v.y + v.z * v.z + v.w * v.w;
#pragma unroll
    for (int off = 16; off; off >>= 1) ss += __shfl_xor(ss, off);  // 32-lane
    float rn = 1.f / fmaxf(sqrtf(ss), 1e-12f);  // F.normalize eps clamp
    float x0 = v.x * rn, x1 = v.y * rn, x2 = v.z * rn, x3 = v.w * rn;

    unsigned pk0 = (unsigned)(unsigned short)f2bf(x0) |
                   ((unsigned)(unsigned short)f2bf(x1) << 16);
    unsigned pk1 = (unsigned)(unsigned short)f2bf(x2) |
                   ((unsigned)(unsigned short)f2bf(x3) << 16);
    int kc = lh >> 1;
    size_t chunk = (size_t)(row >> 4) * 256 + (size_t)(kc >> 2) * 64 +
                   (size_t)(kc & 3) * 16 + (row & 15);
    *(uint2*)(xnbF + chunk * 16 + (lh & 1) * 8) = make_uint2(pk0, pk1);

    int lab = label[row];  // half-wave uniform
    if (lab == 0) {
      a00 += x0; a01 += x1; a02 += x2; a03 += x3;
      if (lh == 0) c0++;
    } else {
      a10 += x0; a11 += x1; a12 += x2; a13 += x3;
      if (lh == 0) c1++;
    }
  }
  int base = lh * 4;  // 8 colliders per address (4 waves x 2 halves)
  atomicAdd(&shg[base + 0], a00); atomicAdd(&shg[base + 1], a01);
  atomicAdd(&shg[base + 2], a02); atomicAdd(&shg[base + 3], a03);
  atomicAdd(&shg[128 + base + 0], a10); atomicAdd(&shg[128 + base + 1], a11);
  atomicAdd(&shg[128 + base + 2], a12); atomicAdd(&shg[128 + base + 3], a13);
  if (lh == 0) { atomicAdd(&shc[0], c0); atomicAdd(&shc[1], c1); }
  __syncthreads();
  // 8-way-split targets: per-address global atomic chain is 32, not 64
  atomicAdd(&gh8[(blockIdx.x & 7) * 256 + tid], shg[tid]);
  if (tid < 2) atomicAdd(&cnt8[(blockIdx.x & 7) * 2 + tid], shc[tid]);
}

// K3: m97-structure Gram-row reductions.
// Round-5 post-mortem: three structures (LDS 2-phase / direct-L2 1-deep /
// 2-deep ping-pong) all ~400 TF-equiv with every pipe <32% busy and
// Occupancy 17% (2 waves/SIMD, register-limited by the 64-row wave tile).
// This version: 32 rows/wave (~120 regs), 8 waves/block (512 thr), B panel
// shared via linear fragment-order LDS (global_load_lds w16, conflict-free
// ds_read_b128), double-buffered, ONE barrier per 64-col tile, and MFMA
// issue order interleaves 4 independent accumulator chains (dep distance 4).
// Target occupancy: 4 waves/SIMD (2 blocks/CU, 64KB LDS) for m114-style
// cross-wave MFMA/VALU/VMEM overlap.
__global__ __launch_bounds__(512, 4) void k_main(const short* __restrict__ xnbF,
                                                 const int* __restrict__ label,
                                                 const float* __restrict__ mf,
                                                 const float* __restrict__ scale,
                                                 float* __restrict__ Zr,
                                                 float* __restrict__ Ur,
                                                 float* __restrict__ Vr) {
  __shared__ short tile[2][64 * DD];  // 2 x 16KB double buffer
  int tid = threadIdx.x, wave = tid >> 6, lane = tid & 63;
  int quad = lane >> 4, col = lane & 15;
  int rbI = blockIdx.x >> 4;  // 0..31: 256-row block (8 waves x 32 rows)
  int sl = blockIdx.x & 15;   // 0..15: 512-col slice (8 tiles of 64)
  float se2 = __expf(scale[0]) * L2E;  // exp(scale)*log2(e): log2-domain logits

  const short8* F = (const short8*)xnbF;  // indexed by 16B chunk

  // A fragments: 2 row-sets of 16 rows (32 rows/wave); scaled by se2 once.
  int gA = rbI * 16 + wave * 2;
  short8 af[2][4];
#pragma unroll
  for (int s = 0; s < 2; ++s)
#pragma unroll
    for (int t = 0; t < 4; ++t) {
      short8 a = F[(size_t)(gA + s) * 256 + t * 64 + lane];
#pragma unroll
      for (int i = 0; i < 8; ++i) a[i] = f2bf(bf2f(a[i]) * se2);
      af[s][t] = a;
    }

  float4v Z0 = {0.f,0.f,0.f,0.f}, Z1 = Z0, U0 = Z0, U1 = Z0, V0 = Z0, V1 = Z0;

  int cb4 = sl * 32;  // chunk-group base of this slice (cols cb4*16)

  // Stage one 64-col tile (16KB = 1024 chunks, contiguous in xnbF) into LDS.
  // 512 threads x 2 x 16B; dst = wave-uniform base + lane*16 (HW requirement).
#define STAGE(buf, jt)                                                         \
  {                                                                            \
    const char* s_ = (const char*)xnbF +                                       \
                     ((size_t)(cb4 + (jt) * 4) * 256 + tid) * 16;              \
    char* d_ = (char*)tile[buf] + tid * 16;                                    \
    __builtin_amdgcn_global_load_lds(                                          \
        (const __attribute__((address_space(1))) void*)(uintptr_t)s_,          \
        (__attribute__((address_space(3))) void*)(uintptr_t)d_, 16, 0, 0);     \
    __builtin_amdgcn_global_load_lds(                                          \
        (const __attribute__((address_space(1))) void*)(uintptr_t)(s_ + 8192), \
        (__attribute__((address_space(3))) void*)(uintptr_t)(d_ + 8192),       \
        16, 0, 0);                                                             \
  }

  STAGE(0, 0);
  __syncthreads();  // barrier drains vmcnt: tile 0 resident

#pragma unroll 1
  for (int jt = 0; jt < 8; ++jt) {
    if (jt < 7) STAGE((jt + 1) & 1, jt + 1);  // in flight over this tile's compute
    const short8* T8 = (const short8*)tile[jt & 1];
    int jcb = sl * 512 + jt * 64;

    // Two half-tiles of 2 col-groups each; 16 MFMAs per half-tile in
    // 4-independent-chain interleave (c00,c01,c10,c11 round-robin).
#define HALFTILE(jo)                                                           \
    {                                                                          \
      short8 b00 = T8[(jo) * 256 + lane];                                      \
      short8 b01 = T8[(jo) * 256 + 64 + lane];                                 \
      short8 b02 = T8[(jo) * 256 + 128 + lane];                                \
      short8 b03 = T8[(jo) * 256 + 192 + lane];                                \
      short8 b10 = T8[(jo + 1) * 256 + lane];                                  \
      short8 b11 = T8[(jo + 1) * 256 + 64 + lane];                             \
      short8 b12 = T8[(jo + 1) * 256 + 128 + lane];                            \
      short8 b13 = T8[(jo + 1) * 256 + 192 + lane];                            \
      float m0 = mf[jcb + (jo) * 16 + col];                                    \
      float m1 = mf[jcb + (jo + 1) * 16 + col];                                \
      float4v c00 = {0.f, 0.f, 0.f, 0.f}, c01 = c00, c10 = c00, c11 = c00;     \
      c00 = __builtin_amdgcn_mfma_f32_16x16x32_bf16(af[0][0], b00, c00, 0,0,0);\
      c01 = __builtin_amdgcn_mfma_f32_16x16x32_bf16(af[1][0], b00, c01, 0,0,0);\
      c10 = __builtin_amdgcn_mfma_f32_16x16x32_bf16(af[0][0], b10, c10, 0,0,0);\
      c11 = __builtin_amdgcn_mfma_f32_16x16x32_bf16(af[1][0], b10, c11, 0,0,0);\
      c00 = __builtin_amdgcn_mfma_f32_16x16x32_bf16(af[0][1], b01, c00, 0,0,0);\
      c01 = __builtin_amdgcn_mfma_f32_16x16x32_bf16(af[1][1], b01, c01, 0,0,0);\
      c10 = __builtin_amdgcn_mfma_f32_16x16x32_bf16(af[0][1], b11, c10, 0,0,0);\
      c11 = __builtin_amdgcn_mfma_f32_16x16x32_bf16(af[1][1], b11, c11, 0,0,0);\
      c00 = __builtin_amdgcn_mfma_f32_16x16x32_bf16(af[0][2], b02, c00, 0,0,0);\
      c01 = __builtin_amdgcn_mfma_f32_16x16x32_bf16(af[1][2], b02, c01, 0,0,0);\
      c10 = __builtin_amdgcn_mfma_f32_16x16x32_bf16(af[0][2], b12, c10, 0,0,0);\
      c11 = __builtin_amdgcn_mfma_f32_16x16x32_bf16(af[1][2], b12, c11, 0,0,0);\
      c00 = __builtin_amdgcn_mfma_f32_16x16x32_bf16(af[0][3], b03, c00, 0,0,0);\
      c01 = __builtin_amdgcn_mfma_f32_16x16x32_bf16(af[1][3], b03, c01, 0,0,0);\
      c10 = __builtin_amdgcn_mfma_f32_16x16x32_bf16(af[0][3], b13, c10, 0,0,0);\
      c11 = __builtin_amdgcn_mfma_f32_16x16x32_bf16(af[1][3], b13, c11, 0,0,0);\
      _Pragma("unroll")                                                        \
      for (int r = 0; r < 4; ++r) { /* C/D: col=lane&15, row=quad*4+r (m89) */ \
        float l, e;                                                            \
        l = c00[r]; e = EXP2(l);  /* log2-domain, |l|<=20.6: fp32-safe */      \
        Z0[r] += e; U0[r] = fmaf(e, l, U0[r]); V0[r] = fmaf(m0, e, V0[r]);     \
        l = c01[r]; e = EXP2(l);                                               \
        Z1[r] += e; U1[r] = fmaf(e, l, U1[r]); V1[r] = fmaf(m0, e, V1[r]);     \
        l = c10[r]; e = EXP2(l);                                               \
        Z0[r] += e; U0[r] = fmaf(e, l, U0[r]); V0[r] = fmaf(m1, e, V0[r]);     \
        l = c11[r]; e = EXP2(l);                                               \
        Z1[r] += e; U1[r] = fmaf(e, l, U1[r]); V1[r] = fmaf(m1, e, V1[r]);     \
      }                                                                        \
    }
    HALFTILE(0)
    HALFTILE(2)
#undef HALFTILE
    __syncthreads();  // drains stage(jt+1); protects tile[jt&1] for overwrite
  }
#undef STAGE

  // reduce across the 16 column-lanes sharing each output row, then atomics
#define EMIT(s, Zc, Uc, Vc)                                                    \
  {                                                                            \
    _Pragma("unroll")                                                          \
    for (int r = 0; r < 4; ++r) {                                              \
      float z = Zc[r], u = Uc[r], v0 = Vc[r];                                  \
      _Pragma("unroll")                                                        \
      for (int off = 1; off < 16; off <<= 1) {                                 \
        z += __shfl_xor(z, off);                                               \
        u += __shfl_xor(u, off);                                               \
        v0 += __shfl_xor(v0, off);                                             \
      }                                                                        \
      if (col == 0) {                                                          \
        int row = rbI * 256 + wave * 32 + s * 16 + quad * 4 + r;               \
        int lab = label[row];                                                  \
        float v = (lab == 0) ? v0 : (z - v0);                                  \
        atomicAdd(&Zr[row], z);                                                \
        atomicAdd(&Ur[row], u * LN2); /* log2-domain -> nats */                \
        atomicAdd(&Vr[row], v);                                                \
      }                                                                        \
    }                                                                          \
  }
  EMIT(0, Z0, U0, V0)
  EMIT(1, Z1, U1, V1)
#undef EMIT
}

// K4: per-row loss; S,T via closed-form dots with class sums. 256 blocks x 32
// rows; per-block partial + agent-scope last-block ticket does the final sum.
__global__ __launch_bounds__(256) void k_final(const float* __restrict__ data,
                                               const int* __restrict__ label,
                                               const float* __restrict__ scale,
                                               const float* __restrict__ gh8,
                                               const int* __restrict__ cnt8,
                                               const float* __restrict__ Zr,
                                               const float* __restrict__ Ur,
                                               const float* __restrict__ Vr,
                                               float* __restrict__ partial,
                                               int* __restrict__ ticket,
                                               float* __restrict__ out) {
  __shared__ float hsum[256];
  __shared__ float bsum[4];
  __shared__ int lastb;
  int tid = threadIdx.x, wave = tid >> 6, lane = tid & 63;
  int lh = lane & 31, rsel = lane >> 5;
  float hs = 0.f;
#pragma unroll
  for (int i = 0; i < 8; ++i) hs += gh8[i * 256 + tid];
  hsum[tid] = hs;
  __syncthreads();

  float se = __expf(scale[0]);
  int ci0 = 0, ci1 = 0;
#pragma unroll
  for (int i = 0; i < 8; ++i) { ci0 += cnt8[2 * i]; ci1 += cnt8[2 * i + 1]; }
  float c0 = (float)ci0, c1 = (float)ci1;
  float4 h0 = *(const float4*)&hsum[lh * 4];
  float4 h1 = *(const float4*)&hsum[128 + lh * 4];

  float local = 0.f;
#pragma unroll
  for (int it = 0; it < 4; ++it) {
    int row = blockIdx.x * 32 + it * 8 + wave * 2 + rsel;
    float4 v = *(const float4*)&data[row * DD + lh * 4];
    float ss = v.x * v.x + v.y * v.y + v.z * v.z + v.w * v.w;
#pragma unroll
    for (int off = 16; off; off >>= 1) ss += __shfl_xor(ss, off);
    float rn = 1.f / fmaxf(sqrtf(ss), 1e-12f);

    int lab = label[row];
    float sg = v.x * (h0.x + h1.x) + v.y * (h0.y + h1.y) +
               v.z * (h0.z + h1.z) + v.w * (h0.w + h1.w);
    float sh_ = (lab == 0)
                    ? (v.x * h0.x + v.y * h0.y + v.z * h0.z + v.w * h0.w)
                    : (v.x * h1.x + v.y * h1.y + v.z * h1.z + v.w * h1.w);
#pragma unroll
    for (int off = 16; off; off >>= 1) {
      sg += __shfl_xor(sg, off);
      sh_ += __shfl_xor(sh_, off);
    }
    if (lh == 0) {
      float cc = (lab == 0) ? c0 : c1;
      float a = __expf(1.f / cc);
      float Zq = cc * a + ((float)BS - cc);
      float S = se * sg * rn, T = se * sh_ * rn;
      float Zv = Zr[row], Uv = Ur[row], Vv = Vr[row];
      // loss_i = a/Zq - (S+(a-1)T)/Zq + U/Z - V/(c*Z)  (M_i, log Zq cancelled)
      local += a / Zq - (S + (a - 1.f) * T) / Zq + Uv / Zv - Vv / (cc * Zv);
    }
  }
  // local is nonzero only on lanes 0 and 32; full-wave reduce is safe
#pragma unroll
  for (int off = 32; off; off >>= 1) local += __shfl_xor(local, off);
  if (lane == 0) bsum[wave] = local;
  __syncthreads();
  if (tid == 0) {
    float psum = bsum[0] + bsum[1] + bsum[2] + bsum[3];
    // agent-scope release store -> visible across XCD L2s at coherence point
    __hip_atomic_store(&partial[blockIdx.x], psum, __ATOMIC_RELEASE,
                       __HIP_MEMORY_SCOPE_AGENT);
    int t = __hip_atomic_fetch_add(ticket, 1, __ATOMIC_ACQ_REL,
                                   __HIP_MEMORY_SCOPE_AGENT);
    lastb = (t == 255);
  }
  __syncthreads();
  if (lastb) {  // last block sums all 256 partials and stores the result
    float v = __hip_atomic_load(&partial[tid], __ATOMIC_ACQUIRE,
                                __HIP_MEMORY_SCOPE_AGENT);
#pragma unroll
    for (int off = 32; off; off >>= 1) v += __shfl_xor(v, off);
    if (lane == 0) bsum[wave] = v;
    __syncthreads();
    if (tid == 0)
      out[0] = (bsum[0] + bsum[1] + bsum[2] + bsum[3]) * (0.5f / (float)BS);
  }
}

extern "C" void kernel_launch(void* const* d_in, const int* in_sizes, int n_in,
                              void* d_out, int out_size, void* d_ws, size_t ws_size,
                              hipStream_t stream) {
  const float* data = (const float*)d_in[0];
  const float* scale = (const float*)d_in[1];
  const int* label = (const int*)d_in[2];
  char* ws = (char*)d_ws;
  // ws layout (bytes):
  //   0        xnbF bf16 fragment-order [8192*128]   2 MB
  //   2097152  Zr      f32 [8192]
  //   2129920  Ur      f32 [8192]
  //   2162688  Vr      f32 [8192]
  //   2195456  gh8     f32 [8][256]  (8-way split class sums)
  //   2203648  cnt8    int [16]      (8-way split class counts)
  //   2203712  ticket  int [1]
  //   2203716  partial f32 [256]
  //   2204800  mf      f32 [8192]
  char* xnbF = ws;
  float* Zr = (float*)(ws + 2097152);
  float* Ur = (float*)(ws + 2129920);
  float* Vr = (float*)(ws + 2162688);
  float* gh8 = (float*)(ws + 2195456);
  int* cnt8 = (int*)(ws + 2203648);
  int* ticket = (int*)(ws + 2203712);
  float* partial = (float*)(ws + 2203716);
  float* mf = (float*)(ws + 2204800);

  // gh8+cnt8+ticket (8260 B); Zr/Ur/Vr/mf zeroed in k_norm; partial fully
  // written by k_final before any read; out stored by k_final's last block.
  hipMemsetAsync(ws + 2195456, 0, 8260, stream);

  k_norm<<<256, 256, 0, stream>>>(data, label, xnbF, gh8, cnt8, Zr, Ur, Vr, mf);
  k_main<<<512, 512, 0, stream>>>((const short*)xnbF, label, mf, scale, Zr, Ur, Vr);
  k_final<<<256, 256, 0, stream>>>(data, label, scale, gh8, cnt8, Zr, Ur, Vr,
                                   partial, ticket, (float*)d_out);
}